// Round 5
// baseline (34.329 us; speedup 1.0000x reference)
//
#include <hip/hip_runtime.h>
#include <math.h>

// NonLinearLayer: piecewise-quadratic CDF flow on a geometric mesh.
// x:(N,16) f32, pdj:(N,1), sldj:(N,1), log_p:(63,16), mesh_norm:(65,), elmt_size:(64,)
// out = concat(x_out (N*16), pdj_out (N), sldj_out (N))
//
// Bin index computed ANALYTICALLY (mesh geometric: boundary i at 1+K1*|x|=1.2^|i|).
// No searchsorted fixup: y and abs_det are continuous across bin boundaries, so a
// +-1 misclassification (only within ~2ulp of a boundary) perturbs output ~1e-5.
//
// R5: sched_barrier(0) after the 8 ds_read_b128 gathers forces them ALL in
// flight before any consumer (R3/R4 lesson: compiler re-serialized them,
// VGPR_Count stuck at 32 => ~8x130cyc exposed LDS latency per iter).
// Next-iteration global loads are software-prefetched at loop top.

namespace {
constexpr int DIM = 16;
constexpr int ME  = 64;
constexpr float BOUNDF = 50.0f;
// K1 = 0.2/one_step = 0.02*(1.2^32-1);  INV_L2R = 1/log2(1.2)
constexpr float K1      = 6.8164378f;
constexpr float INV_L2R = 3.8017840f;
constexpr int COEF_FLOATS = ME * 68;                 // (A,B,D,2A)[bin][dim], stride 68 floats
constexpr int EP_BASE     = COEF_FLOATS - 63 * DIM;  // transient exp(log_p) scratch in tail
}

__global__ __launch_bounds__(256) void nll_kernel(
    const float* __restrict__ x,
    const float* __restrict__ pdj,
    const float* __restrict__ sldj,
    const float* __restrict__ log_p,
    const float* __restrict__ mesh_norm,
    float* __restrict__ out,
    int npts, int npairs)
{
  __shared__ __align__(16) float co[COEF_FLOATS];
  __shared__ float s_mesh[ME + 1];

  const int tid = threadIdx.x;

  // ---- setup phase 1: loads + exp (fully parallel) ----
  if (tid <= ME) s_mesh[tid] = mesh_norm[tid];
  for (int i = tid; i < 63 * DIM; i += 256)
    co[EP_BASE + i] = __expf(log_p[i]);
  __syncthreads();

  // ---- setup phase 2a: stash ep columns in regs (scratch overwritten in 2b) ----
  const int wv = tid >> 6, lane = tid & 63;
  float epv[4];
#pragma unroll
  for (int i = 0; i < 4; ++i)
    epv[i] = (lane < 63) ? co[EP_BASE + lane * DIM + (4 * wv + i)] : 0.f;
  const float mj  = s_mesh[lane];
  const float mj1 = s_mesh[lane + 1];
  const float mj2 = s_mesh[(lane + 2 > ME) ? ME : (lane + 2)];
  const float es0 = s_mesh[1] - s_mesh[0];
  __syncthreads();

  // ---- setup phase 2b: wave-parallel normalize + prefix scan, 4 dims/wave ----
  const float h = mj1 - mj;
#pragma unroll
  for (int i = 0; i < 4; ++i) {
    const int d = 4 * wv + i;
    const float ep = epv[i];
    float ss = (lane < 63) ? ep * (mj2 - mj) : 0.f;
    ss += __shfl_xor(ss, 1);  ss += __shfl_xor(ss, 2);  ss += __shfl_xor(ss, 4);
    ss += __shfl_xor(ss, 8);  ss += __shfl_xor(ss, 16); ss += __shfl_xor(ss, 32);
    const float scale = (1.0f - es0) / (0.5f * ss);
    const float cur = (lane < 63) ? ep * scale : 1.0f;   // pdf_norm[lane+1]
    float prev = __shfl_up(cur, 1);                       // pdf_norm[lane]
    if (lane == 0) prev = 1.0f;
    const float cell = (prev + cur) * 0.5f * h;
    float v = cell, o;
    o = __shfl_up(v, 1);  if (lane >= 1)  v += o;
    o = __shfl_up(v, 2);  if (lane >= 2)  v += o;
    o = __shfl_up(v, 4);  if (lane >= 4)  v += o;
    o = __shfl_up(v, 8);  if (lane >= 8)  v += o;
    o = __shfl_up(v, 16); if (lane >= 16) v += o;
    o = __shfl_up(v, 32); if (lane >= 32) v += o;
    const float F = v - cell;                             // exclusive prefix = F_ref[lane]
    const float A = 0.5f * (cur - prev) / h;
    const float B = fmaf(-(A + A), mj, prev);
    const float D = fmaf(mj, fmaf(mj, A, -prev), F);
    *reinterpret_cast<float4*>(&co[lane * 68 + 4 * d]) = make_float4(A, B, D, A + A);
  }
  __syncthreads();

  // ---- main loop: 8 elements (half a point) per thread, prefetched ----
  const int tpg = gridDim.x * blockDim.x;
  const float4* __restrict__ x4 = reinterpret_cast<const float4*>(x);
  float4* __restrict__ out4 = reinterpret_cast<float4*>(out);
  const int np16 = npts * DIM;

  int t = blockIdx.x * blockDim.x + tid;
  if (t >= npairs) return;

  // preload first tile
  float4 xa = x4[2 * t];
  float4 xb = x4[2 * t + 1];
  float   ps = (t & 1) ? sldj[t >> 1] : pdj[t >> 1];

  while (true) {
    const int tn = t + tpg;
    const bool more = tn < npairs;

    // prefetch next tile (global latency hides under this iteration's work)
    float4 xa_n, xb_n;
    float  ps_n = 0.f;
    if (more) {
      xa_n = x4[2 * tn];
      xb_n = x4[2 * tn + 1];
      ps_n = (tn & 1) ? sldj[tn >> 1] : pdj[tn >> 1];
    }

    const int p  = t >> 1;
    const int hh = t & 1;              // half: dims hh*8 .. hh*8+7
    const float vals[8] = {xa.x, xa.y, xa.z, xa.w, xb.x, xb.y, xb.z, xb.w};

    // phase A: indices (8 independent VALU chains)
    float xn[8];
    int   off[8];
#pragma unroll
    for (int j = 0; j < 8; ++j) {
      const float val = vals[j];
      xn[j] = (val + BOUNDF) * 0.01f;
      const float u = fmaf(fabsf(val), K1, 1.0f);
      const float n = __log2f(u) * INV_L2R;
      int km1 = 31 + (int)ceilf(copysignf(n, val));
      km1 = km1 < 0 ? 0 : (km1 > 63 ? 63 : km1);
      off[j] = km1 * 68 + (((hh << 3) + j) << 2);
    }

    // phase B: 8 batched LDS gathers — fence below keeps them ALL in flight
    float4 cf[8];
#pragma unroll
    for (int j = 0; j < 8; ++j)
      cf[j] = *reinterpret_cast<const float4*>(&co[off[j]]);
    __builtin_amdgcn_sched_barrier(0);

    // phase C: math + pairwise product tree
    float yv[8], dt[8];
#pragma unroll
    for (int j = 0; j < 8; ++j) {
      const float z = xn[j];
      float y = fmaf(z, fmaf(z, cf[j].x, cf[j].y), cf[j].z);
      float d = fmaf(z, cf[j].w, cf[j].y);
      const bool cover = (z > 0.f) && (z <= 1.0f);
      y = cover ? y : z;
      d = cover ? d : 1.0f;
      yv[j] = fmaf(y, 2.0f * BOUNDF, -BOUNDF);
      dt[j] = d;
    }
    const float prod = ((dt[0] * dt[1]) * (dt[2] * dt[3])) *
                       ((dt[4] * dt[5]) * (dt[6] * dt[7]));

    out4[2 * t]     = make_float4(yv[0], yv[1], yv[2], yv[3]);
    out4[2 * t + 1] = make_float4(yv[4], yv[5], yv[6], yv[7]);

    const float full = prod * __shfl_xor(prod, 1);
    const float res  = hh ? (ps + __logf(full)) : (ps * full);
    out[np16 + hh * npts + p] = res;

    if (!more) break;
    t = tn; xa = xa_n; xb = xb_n; ps = ps_n;
  }
}

extern "C" void kernel_launch(void* const* d_in, const int* in_sizes, int n_in,
                              void* d_out, int out_size, void* d_ws, size_t ws_size,
                              hipStream_t stream) {
  const float* x    = (const float*)d_in[0];
  const float* pdj  = (const float*)d_in[1];
  const float* sldj = (const float*)d_in[2];
  const float* lp   = (const float*)d_in[3];
  const float* mesh = (const float*)d_in[4];
  float* out = (float*)d_out;

  const int npts   = in_sizes[0] / DIM;
  const int npairs = npts * 2;
  const int block  = 256;
  int grid = 2048;
  const int needed = (npairs + block - 1) / block;
  if (needed < grid) grid = needed;

  hipLaunchKernelGGL(nll_kernel, dim3(grid), dim3(block), 0, stream,
                     x, pdj, sldj, lp, mesh, out, npts, npairs);
}